// Round 4
// baseline (431.729 us; speedup 1.0000x reference)
//
#include <hip/hip_runtime.h>

// Holt double-exponential smoothing, chunk-parallel decomposition.
//
// Recurrence (t>=2): s = 0.5*x + 0.5*(s_p + b_p); b = 0.5*(s - s_p) + 0.5*b_p
// is affine: state_t = A * state_{t-1} + (0.5 x, 0.25 x),
//   A = [[0.5, 0.5], [-0.25, 0.75]], |eigenvalues| = sqrt(0.5).
// Split each T=1024 sequence into C=16 chunks of L=64:
//   Phase A: per-chunk zero-init run (x held in registers) -> chunk-final state
//   Phase B: per-sequence serial scan over chunk states with constant A^64
//   Phase C: exact sequential recurrence from corrected init, outputs -> regs
//   Phase D: chunk-partitioned LDS stages; each global store instruction is
//            1 KiB fully contiguous lane-ordered (fillBufferAligned's shape).
//
// BARRIER-FREE (this round): wave wv owns tids [wv*64, wv*64+64) = sequences
// wv*4..wv*4+3 with all 16 chunks -> Phase B's scan and Phase D's transpose
// are wave-closed. Every __syncthreads() (which forces a vmcnt(0) drain,
// stalling the store pipeline 4x per wave) is replaced by a wave-local
// s_waitcnt lgkmcnt(0). The kernel now has NO barriers and NO vmcnt waits:
// all 16 store instructions per wave stay in flight.
//
// History:
//   R0: strided 16B stores, WRITE=2x, ~200us kernel.
//   R1: gg-partitioned transpose (16x64B segs/instr): WRITE still 2x, but
//       request-path relief -> ~139us.
//   R2: + full-line loads (Phase L): FETCH 137->241 GB (lost cross-iteration
//       L3 input residency) -> REGRESSION, reverted.
//   R3: chunk-partitioned stages + fill-shaped 1KiB stores -> ~99us.
// Quirky init (faithful to reference): out[0]=0; out[1]=x[1] with NO state
// update; state entering t=2 is (0,0).

constexpr int T_STEPS = 1024;
constexpr int CHUNKS  = 16;            // chunks per sequence
constexpr int CLEN    = T_STEPS / CHUNKS;  // 64 steps per chunk
constexpr int CGROUPS = CLEN / 4;      // 16 float4 groups per chunk
constexpr int SEQ_PER_BLOCK = 256 / CHUNKS; // 16 sequences per block

// Compile-time A^64 in double precision.
struct Md { double a00, a01, a10, a11; };
constexpr Md apow(int n) {
    Md p{1.0, 0.0, 0.0, 1.0};
    const Md A{0.5, 0.5, -0.25, 0.75};
    for (int i = 0; i < n; ++i) {
        Md q{A.a00 * p.a00 + A.a01 * p.a10,
             A.a00 * p.a01 + A.a01 * p.a11,
             A.a10 * p.a00 + A.a11 * p.a10,
             A.a10 * p.a01 + A.a11 * p.a11};
        p = q;
    }
    return p;
}
constexpr Md P64 = apow(64);

// Wave-local LDS fence: producer and consumer are the SAME wave, so a
// lgkmcnt(0) wait (with a compiler memory fence) replaces __syncthreads.
// No vmcnt drain -> global stores stay in flight.
#define WAVE_SYNC() asm volatile("s_waitcnt lgkmcnt(0)" ::: "memory")

__global__ __launch_bounds__(256)
void holt_chunked_kernel(const float* __restrict__ x, float* __restrict__ out) {
    const int tid   = threadIdx.x;
    const int chunk = tid & (CHUNKS - 1);
    const int sloc  = tid >> 4;  // local sequence index, 0..15
    const int lane  = tid & 63;
    const int wv    = tid >> 6;
    const size_t seqBase = (size_t)blockIdx.x * SEQ_PER_BLOCK;
    const size_t base = (seqBase + sloc) * T_STEPS + (size_t)chunk * CLEN;

    // ---- Loads: per-thread strided float4 (R1/R3 pattern). Keeps the ~50%
    // cross-iteration L3 input residency (FETCH ~137 GB) that Phase L lost.
    const float4* __restrict__ xv = reinterpret_cast<const float4*>(x + base);
    float4 v[CGROUPS];
#pragma unroll
    for (int g = 0; g < CGROUPS; ++g) v[g] = xv[g];

    float s = 0.0f, b = 0.0f;
    auto step = [&](float xval) {
        float sn = 0.5f * xval + 0.5f * (s + b);
        b = 0.5f * (sn - s) + 0.5f * b;
        s = sn;
    };

    // ---- Phase A: zero-init run, final state only ----
    if (chunk == 0) {
        // t=0: no update; t=1: no state update (quirky init); t=2,3: normal.
        step(v[0].z); step(v[0].w);
    } else {
        step(v[0].x); step(v[0].y); step(v[0].z); step(v[0].w);
    }
#pragma unroll
    for (int g = 1; g < CGROUPS; ++g) {
        step(v[g].x); step(v[g].y); step(v[g].z); step(v[g].w);
    }

    __shared__ float lS[256];
    __shared__ float lB[256];
    lS[tid] = s;
    lB[tid] = b;
    WAVE_SYNC();

    // ---- Phase B: per-sequence scan over chunk states, WAVE-LOCAL ----
    // Lane l (l<4) of wave wv scans sequence wv*4+l, whose 16 chunk states
    // live at lS[wv*64 + l*16 + j] -- produced by this wave.
    if (lane < 4) {
        const int o = wv * 64 + lane * 16;
        const float p00 = (float)P64.a00, p01 = (float)P64.a01;
        const float p10 = (float)P64.a10, p11 = (float)P64.a11;
        float ts = lS[o], tb = lB[o];  // true state after chunk 0
        lS[o] = 0.0f; lB[o] = 0.0f;    // init for chunk 0
        for (int j = 1; j < CHUNKS; ++j) {
            float us = lS[o + j], ub = lB[o + j];
            lS[o + j] = ts;  lB[o + j] = tb;   // init state for chunk j
            float ns = us + p00 * ts + p01 * tb;
            float nb = ub + p10 * ts + p11 * tb;
            ts = ns; tb = nb;
        }
    }
    WAVE_SYNC();

    // ---- Phase C: exact recurrence from corrected init; outputs -> v[] ----
    s = lS[tid];   // lS[sloc*16 + chunk] == lS[tid]
    b = lB[tid];

    {
        float4 o0;
        if (chunk == 0) {
            o0.x = 0.0f;      // t=0
            o0.y = v[0].y;    // t=1 (state not updated)
            step(v[0].z); o0.z = s;
            step(v[0].w); o0.w = s;
        } else {
            step(v[0].x); o0.x = s;
            step(v[0].y); o0.y = s;
            step(v[0].z); o0.z = s;
            step(v[0].w); o0.w = s;
        }
        v[0] = o0;
    }
#pragma unroll
    for (int g = 1; g < CGROUPS; ++g) {
        float4 o;
        step(v[g].x); o.x = s;
        step(v[g].y); o.y = s;
        step(v[g].z); o.z = s;
        step(v[g].w); o.w = s;
        v[g] = o;
    }

    // ---- Phase D: chunk-partitioned stages + fill-shaped stores ----
    // Stage k holds chunks 4k..4k+3 (all 16 gg) of all 16 sequences.
    // Wave-closed: wave wv's producers (tids wv*64..wv*64+63 with chunk>>2==k)
    // fill rows seqL = wv*4..wv*4+3, which only wave wv's consumers read.
    // Producer swizzle f = (cloc<<1)|(sloc&1): 2 lanes/bank-group (free).
    // Consumer: lane l reads (seqL, cloc=l>>4, gg=l&15) -- permutation of 64
    // consecutive f4 slots -- and stores out_f4[seq*256 + k*64 + l]:
    // 1 KiB contiguous lane-ordered, 8 complete 128B lines per instruction.
    __shared__ float4 xfer[SEQ_PER_BLOCK * CHUNKS * 4];  // 1024 float4 = 16 KB

    const int cloc  = chunk & 3;
    const int kown  = chunk >> 2;
    const int fprod = (cloc << 1) | (sloc & 1);
    const int ccl   = lane >> 4;   // consumer chunk-within-stage
    const int cgg   = lane & 15;   // consumer f4-within-chunk
    float4* __restrict__ ov4 = reinterpret_cast<float4*>(out);

#pragma unroll
    for (int k = 0; k < 4; ++k) {
        if (kown == k) {
#pragma unroll
            for (int gg = 0; gg < CGROUPS; ++gg) {
                xfer[sloc * 64 + cloc * 16 + (gg ^ fprod)] = v[gg];
            }
        }
        WAVE_SYNC();   // producer ds_writes visible to this wave's reads
#pragma unroll
        for (int r = 0; r < 4; ++r) {
            const int seqL = wv * 4 + r;
            const float4 val =
                xfer[seqL * 64 + ccl * 16 + (cgg ^ ((ccl << 1) | (seqL & 1)))];
            ov4[(seqBase + seqL) * (T_STEPS / 4) + k * 64 + lane] = val;
        }
        WAVE_SYNC();   // WAR guard: reads done before next stage overwrites
    }
}

extern "C" void kernel_launch(void* const* d_in, const int* in_sizes, int n_in,
                              void* d_out, int out_size, void* d_ws, size_t ws_size,
                              hipStream_t stream) {
    const float* x = (const float*)d_in[0];
    float* out = (float*)d_out;

    const int nseq = in_sizes[0] / T_STEPS;          // 65536
    const int grid = nseq / SEQ_PER_BLOCK;           // 4096 blocks

    holt_chunked_kernel<<<grid, 256, 0, stream>>>(x, out);
}